// Round 5
// baseline (400.229 us; speedup 1.0000x reference)
//
#include <hip/hip_runtime.h>
#include <hip/hip_bf16.h>

#define D_MODEL 1536
#define NEXP    64
#define D_HID   512
#define NTOK    4096
#define NK1     (D_MODEL / 64)   // 24
#define NK2     (D_HID / 64)     // 8
#define MT      192              // packed M rows per block pass

typedef __attribute__((ext_vector_type(8))) short short8;
typedef __attribute__((ext_vector_type(4))) float f32x4;

__device__ __forceinline__ unsigned short f2bf(float f) {
  unsigned u = __builtin_bit_cast(unsigned, f);
  u += 0x7FFFu + ((u >> 16) & 1u);
  return (unsigned short)(u >> 16);
}

__device__ __forceinline__ unsigned pk2(float a, float b) {
  return (unsigned)f2bf(a) | ((unsigned)f2bf(b) << 16);
}

// ---------------- utility ----------------

__global__ void zero_small_kernel(int* __restrict__ counts) {
  counts[threadIdx.x] = 0;
}

// ---------------- router (fp32, LDS-tiled, 8 tokens/block, fused x->bf16) ----------------

__global__ __launch_bounds__(256) void router_kernel(const float* __restrict__ x,
    const float* __restrict__ Wr, int* __restrict__ topidx, float* __restrict__ topw,
    int* __restrict__ counts, unsigned short* __restrict__ xb)
{
  __shared__ float xs[8][32];
  __shared__ float wst[32][64];
  const int tid  = threadIdx.x;
  const int lane = tid & 63;
  const int wv   = tid >> 6;
  const int t0   = blockIdx.x * 8;

  float acc[2][4];
  #pragma unroll
  for (int i = 0; i < 2; ++i)
    #pragma unroll
    for (int j = 0; j < 4; ++j) acc[i][j] = 0.f;

  for (int k0 = 0; k0 < D_MODEL; k0 += 32) {
    __syncthreads();
    {
      int r = tid >> 5, c = tid & 31;
      float xv = x[(long)(t0 + r) * D_MODEL + k0 + c];
      xs[r][c] = xv;
      xb[(long)(t0 + r) * D_MODEL + k0 + c] = f2bf(xv);   // fused conversion
    }
    {
      int e = tid >> 2, q = tid & 3;
      const float* wp = Wr + (long)e * D_MODEL + k0 + q * 8;
      float4 v0 = *(const float4*)wp;
      float4 v1 = *(const float4*)(wp + 4);
      int kk = q * 8;
      wst[kk + 0][e] = v0.x; wst[kk + 1][e] = v0.y; wst[kk + 2][e] = v0.z; wst[kk + 3][e] = v0.w;
      wst[kk + 4][e] = v1.x; wst[kk + 5][e] = v1.y; wst[kk + 6][e] = v1.z; wst[kk + 7][e] = v1.w;
    }
    __syncthreads();
    #pragma unroll
    for (int k = 0; k < 32; k += 4) {
      #pragma unroll
      for (int kb = 0; kb < 4; ++kb) {
        float wvv = wst[k + kb][lane];
        #pragma unroll
        for (int i = 0; i < 2; ++i)
          acc[i][kb] = fmaf(xs[wv * 2 + i][k + kb], wvv, acc[i][kb]);
      }
    }
  }
  float lg[2];
  #pragma unroll
  for (int i = 0; i < 2; ++i) lg[i] = (acc[i][0] + acc[i][1]) + (acc[i][2] + acc[i][3]);

  for (int i = 0; i < 2; ++i) {
    float v = lg[i];
    float v0 = v; int e0 = lane;
    #pragma unroll
    for (int off = 32; off > 0; off >>= 1) {
      float ov = __shfl_xor(v0, off);
      int   oe = __shfl_xor(e0, off);
      if (ov > v0 || (ov == v0 && oe < e0)) { v0 = ov; e0 = oe; }
    }
    float v1 = (lane == e0) ? -3.0e38f : v;
    int e1 = lane;
    #pragma unroll
    for (int off = 32; off > 0; off >>= 1) {
      float ov = __shfl_xor(v1, off);
      int   oe = __shfl_xor(e1, off);
      if (ov > v1 || (ov == v1 && oe < e1)) { v1 = ov; e1 = oe; }
    }
    if (lane == 0) {
      int t = t0 + wv * 2 + i;
      float w0 = 1.f / (1.f + expf(v1 - v0));
      topidx[t * 2]     = e0;
      topidx[t * 2 + 1] = e1;
      topw[t * 2]       = w0;
      topw[t * 2 + 1]   = 1.f - w0;
      atomicAdd(&counts[e0], 1);
      atomicAdd(&counts[e1], 1);
    }
  }
}

// ---------------- scan + scatter ----------------

__global__ void scan_kernel(const int* __restrict__ counts, int* __restrict__ offs,
                            int* __restrict__ cursor)
{
  int e = threadIdx.x;   // 64 threads
  int c = counts[e];
  int xx = c;
  #pragma unroll
  for (int off = 1; off < 64; off <<= 1) {
    int y = __shfl_up(xx, off);
    if (e >= off) xx += y;
  }
  offs[e + 1] = xx;
  if (e == 0) offs[0] = 0;
  cursor[e] = 0;
}

__global__ void scatter_kernel(const int* __restrict__ topidx, const float* __restrict__ topw,
    const int* __restrict__ offs, int* __restrict__ cursor,
    int* __restrict__ perm, float* __restrict__ wgt, int* __restrict__ tok2slot)
{
  int t = blockIdx.x * blockDim.x + threadIdx.x;
  if (t >= NTOK) return;
  #pragma unroll
  for (int k = 0; k < 2; ++k) {
    int e = topidx[t * 2 + k];
    float w = topw[t * 2 + k];
    int pos = atomicAdd(&cursor[e], 1);
    int slot = offs[e] + pos;
    perm[slot] = t;
    wgt[slot] = w;
    tok2slot[t * 2 + k] = slot;
  }
}

// ---------------- ffn1: B-only LDS, A direct from L3-resident xb ----------------
// grid (64 experts, 16 chunks of 32 cols), 256 thr, 4 waves x 48 rows

__global__ __launch_bounds__(256, 4) void ffn1_kernel(
    const unsigned short* __restrict__ xb, const float* __restrict__ W1,
    const int* __restrict__ offs, const int* __restrict__ perm,
    const float* __restrict__ wgt, unsigned short* __restrict__ hbuf)
{
  const int e  = blockIdx.x;
  const int nc = blockIdx.y;                  // 0..15 : 32-col chunk of D_HID
  const int cnt = offs[e + 1] - offs[e];
  if (cnt == 0) return;

  __shared__ unsigned short Bs[2][32 * 64];

  const int tid = threadIdx.x;
  const int lane = tid & 63;
  const int wv = tid >> 6;

  const int qB = tid & 15;
  const int rB = tid >> 4;
  const float* bptr[2];
  #pragma unroll
  for (int p = 0; p < 2; ++p)
    bptr[p] = W1 + ((long)e * D_HID + nc * 32 + p * 16 + rB) * D_MODEL + qB * 4;

  int brow[2], physB[2][2];
  #pragma unroll
  for (int ni = 0; ni < 2; ++ni) {
    brow[ni] = ni * 16 + (lane & 15);
    #pragma unroll
    for (int ks = 0; ks < 2; ++ks)
      physB[ks][ni] = (ks * 4 + (lane >> 4)) ^ (brow[ni] & 7);
  }
  const int kq = (lane >> 4) * 8;

  float4 breg[2];
  auto LOADB = [&](int k0) {
    breg[0] = *(const float4*)(bptr[0] + k0);
    breg[1] = *(const float4*)(bptr[1] + k0);
  };
  auto WRITEB = [&](int b) {
    #pragma unroll
    for (int p = 0; p < 2; ++p) {
      int rr = p * 16 + rB;
      unsigned lo = pk2(breg[p].x, breg[p].y);
      unsigned hi = pk2(breg[p].z, breg[p].w);
      int ph = (qB >> 1) ^ (rr & 7);
      *(uint2*)(&Bs[b][rr * 64 + ph * 8 + (qB & 1) * 4]) = make_uint2(lo, hi);
    }
  };

  for (int m0 = 0; m0 < cnt; m0 += MT) {
    const int base = offs[e] + m0;
    const int mcnt = min(MT, cnt - m0);

    const unsigned short* rowp[3];
    #pragma unroll
    for (int mi = 0; mi < 3; ++mi) {
      int pr = wv * 48 + mi * 16 + (lane & 15);
      if (pr >= mcnt) pr = mcnt - 1;            // clamp: garbage rows discarded in epilogue
      rowp[mi] = xb + (long)perm[base + pr] * D_MODEL + kq;
    }

    f32x4 acc[3][2];
    #pragma unroll
    for (int i = 0; i < 3; ++i)
      #pragma unroll
      for (int j = 0; j < 2; ++j) acc[i][j] = (f32x4)0.f;

    short8 aA[6], aB[6];
    auto LOADA = [&](short8* d, int k0) {
      #pragma unroll
      for (int mi = 0; mi < 3; ++mi)
        #pragma unroll
        for (int ks = 0; ks < 2; ++ks)
          d[mi * 2 + ks] = *(const short8*)(rowp[mi] + k0 + ks * 32);
    };
    auto COMP = [&](int b, const short8* a) {
      #pragma unroll
      for (int ks = 0; ks < 2; ++ks) {
        short8 bb[2];
        #pragma unroll
        for (int ni = 0; ni < 2; ++ni)
          bb[ni] = *(const short8*)(&Bs[b][brow[ni] * 64 + physB[ks][ni] * 8]);
        #pragma unroll
        for (int mi = 0; mi < 3; ++mi)
          #pragma unroll
          for (int ni = 0; ni < 2; ++ni)
            acc[mi][ni] = __builtin_amdgcn_mfma_f32_16x16x32_bf16(a[mi * 2 + ks], bb[ni], acc[mi][ni], 0, 0, 0);
      }
    };

    LOADB(0); LOADA(aA, 0); WRITEB(0);
    __syncthreads();
    #pragma unroll 1
    for (int t = 0; t < NK1; t += 2) {
      LOADB((t + 1) * 64); LOADA(aB, (t + 1) * 64);
      COMP(0, aA);
      WRITEB(1); __syncthreads();
      if (t + 2 < NK1) { LOADB((t + 2) * 64); LOADA(aA, (t + 2) * 64); }
      COMP(1, aB);
      if (t + 2 < NK1) { WRITEB(0); __syncthreads(); }
    }

    // epilogue: SiLU * gate -> bf16 hbuf
    const int rsub = (lane >> 4) * 4;
    const int csub = lane & 15;
    #pragma unroll
    for (int mi = 0; mi < 3; ++mi) {
      #pragma unroll
      for (int rg = 0; rg < 4; ++rg) {
        int r = wv * 48 + mi * 16 + rsub + rg;
        if (r < mcnt) {
          float wt = wgt[base + r];
          unsigned short* hrow = hbuf + (long)(base + r) * D_HID + nc * 32 + csub;
          #pragma unroll
          for (int ni = 0; ni < 2; ++ni) {
            float v = acc[mi][ni][rg];
            float sv = v / (1.f + __expf(-v)) * wt;
            hrow[ni * 16] = f2bf(sv);
          }
        }
      }
    }
    __syncthreads();
  }
}

// ---------------- ffn2: B-only LDS, A direct from L3-resident hbuf ----------------
// grid (64 experts, 24 chunks of 64 cols), 256 thr, 4 waves x 48 rows

__global__ __launch_bounds__(256, 3) void ffn2_kernel(
    const unsigned short* __restrict__ hbuf, const float* __restrict__ W2,
    const int* __restrict__ offs, float* __restrict__ sbuf)
{
  const int e  = blockIdx.x;
  const int nc = blockIdx.y;                  // 0..23 : 64-col chunk of D_MODEL
  const int cnt = offs[e + 1] - offs[e];
  if (cnt == 0) return;

  __shared__ unsigned short Bs[2][64 * 64];

  const int tid = threadIdx.x;
  const int lane = tid & 63;
  const int wv = tid >> 6;

  const int qB = tid & 15;
  const int rB = tid >> 4;
  const float* bptr[4];
  #pragma unroll
  for (int p = 0; p < 4; ++p)
    bptr[p] = W2 + ((long)e * D_MODEL + nc * 64 + p * 16 + rB) * D_HID + qB * 4;

  int brow[4], physB[2][4];
  #pragma unroll
  for (int ni = 0; ni < 4; ++ni) {
    brow[ni] = ni * 16 + (lane & 15);
    #pragma unroll
    for (int ks = 0; ks < 2; ++ks)
      physB[ks][ni] = (ks * 4 + (lane >> 4)) ^ (brow[ni] & 7);
  }
  const int kq = (lane >> 4) * 8;

  float4 breg[4];
  auto LOADB = [&](int k0) {
    #pragma unroll
    for (int p = 0; p < 4; ++p)
      breg[p] = *(const float4*)(bptr[p] + k0);
  };
  auto WRITEB = [&](int b) {
    #pragma unroll
    for (int p = 0; p < 4; ++p) {
      int rr = p * 16 + rB;
      unsigned lo = pk2(breg[p].x, breg[p].y);
      unsigned hi = pk2(breg[p].z, breg[p].w);
      int ph = (qB >> 1) ^ (rr & 7);
      *(uint2*)(&Bs[b][rr * 64 + ph * 8 + (qB & 1) * 4]) = make_uint2(lo, hi);
    }
  };

  for (int m0 = 0; m0 < cnt; m0 += MT) {
    const int base = offs[e] + m0;
    const int mcnt = min(MT, cnt - m0);

    const unsigned short* rowp[3];
    #pragma unroll
    for (int mi = 0; mi < 3; ++mi) {
      int pr = wv * 48 + mi * 16 + (lane & 15);
      if (pr >= mcnt) pr = mcnt - 1;
      rowp[mi] = hbuf + (long)(base + pr) * D_HID + kq;
    }

    f32x4 acc[3][4];
    #pragma unroll
    for (int i = 0; i < 3; ++i)
      #pragma unroll
      for (int j = 0; j < 4; ++j) acc[i][j] = (f32x4)0.f;

    short8 aA[6], aB[6];
    auto LOADA = [&](short8* d, int k0) {
      #pragma unroll
      for (int mi = 0; mi < 3; ++mi)
        #pragma unroll
        for (int ks = 0; ks < 2; ++ks)
          d[mi * 2 + ks] = *(const short8*)(rowp[mi] + k0 + ks * 32);
    };
    auto COMP = [&](int b, const short8* a) {
      #pragma unroll
      for (int ks = 0; ks < 2; ++ks) {
        short8 bb[4];
        #pragma unroll
        for (int ni = 0; ni < 4; ++ni)
          bb[ni] = *(const short8*)(&Bs[b][brow[ni] * 64 + physB[ks][ni] * 8]);
        #pragma unroll
        for (int mi = 0; mi < 3; ++mi)
          #pragma unroll
          for (int ni = 0; ni < 4; ++ni)
            acc[mi][ni] = __builtin_amdgcn_mfma_f32_16x16x32_bf16(a[mi * 2 + ks], bb[ni], acc[mi][ni], 0, 0, 0);
      }
    };

    LOADB(0); LOADA(aA, 0); WRITEB(0);
    __syncthreads();
    #pragma unroll 1
    for (int t = 0; t < NK2; t += 2) {
      LOADB((t + 1) * 64); LOADA(aB, (t + 1) * 64);
      COMP(0, aA);
      WRITEB(1); __syncthreads();
      if (t + 2 < NK2) { LOADB((t + 2) * 64); LOADA(aA, (t + 2) * 64); }
      COMP(1, aB);
      if (t + 2 < NK2) { WRITEB(0); __syncthreads(); }
    }

    // epilogue: per-wave LDS transpose (bank-swizzled) -> coalesced float4 stores
    __syncthreads();                        // all waves done reading Bs
    float* myf = (float*)(&Bs[0][0]) + wv * 1024;   // 16 rows x 64 cols per wave
    const int rsub = (lane >> 4) * 4;
    const int csub = lane & 15;
    #pragma unroll 1
    for (int mi = 0; mi < 3; ++mi) {
      #pragma unroll
      for (int rg = 0; rg < 4; ++rg) {
        int row = rsub + rg;
        int sx = ((row >> 2) & 3) << 3;
        #pragma unroll
        for (int ni = 0; ni < 4; ++ni)
          myf[row * 64 + ((ni * 16 + csub) ^ sx)] = acc[mi][ni][rg];
      }
      __syncthreads();
      #pragma unroll
      for (int q = 0; q < 4; ++q) {
        int idx = q * 64 + lane;
        int row = idx >> 4, c4 = idx & 15;
        int gr = wv * 48 + mi * 16 + row;
        int g = c4 ^ (((row >> 2) & 3) << 1);
        if (gr < mcnt)
          *(float4*)(sbuf + (long)(base + gr) * D_MODEL + nc * 64 + c4 * 4) =
              *(const float4*)(myf + row * 64 + g * 4);
      }
      __syncthreads();
    }
  }
}

// ---------------- gather + LayerNorm ----------------

__global__ __launch_bounds__(192) void ln_kernel(const float* __restrict__ sbuf,
    const int* __restrict__ tok2slot, float* __restrict__ out,
    const float* __restrict__ gamma, const float* __restrict__ beta)
{
  const int tid = threadIdx.x;
  const int t = blockIdx.x;
  const long r0 = (long)tok2slot[t * 2]     * D_MODEL;
  const long r1 = (long)tok2slot[t * 2 + 1] * D_MODEL;

  float4 a0 = *(const float4*)(sbuf + r0 + tid * 8);
  float4 a1 = *(const float4*)(sbuf + r0 + tid * 8 + 4);
  float4 b0 = *(const float4*)(sbuf + r1 + tid * 8);
  float4 b1 = *(const float4*)(sbuf + r1 + tid * 8 + 4);
  float4 a = make_float4(a0.x + b0.x, a0.y + b0.y, a0.z + b0.z, a0.w + b0.w);
  float4 b = make_float4(a1.x + b1.x, a1.y + b1.y, a1.z + b1.z, a1.w + b1.w);

  float s  = ((a.x + a.y) + (a.z + a.w)) + ((b.x + b.y) + (b.z + b.w));
  float sq = ((a.x * a.x + a.y * a.y) + (a.z * a.z + a.w * a.w)) +
             ((b.x * b.x + b.y * b.y) + (b.z * b.z + b.w * b.w));
  #pragma unroll
  for (int off = 32; off > 0; off >>= 1) {
    s  += __shfl_xor(s, off);
    sq += __shfl_xor(sq, off);
  }
  __shared__ float ss[3], sqs[3];
  int wv = tid >> 6;
  if ((tid & 63) == 0) { ss[wv] = s; sqs[wv] = sq; }
  __syncthreads();
  s  = ss[0] + ss[1] + ss[2];
  sq = sqs[0] + sqs[1] + sqs[2];
  const float inv = 1.f / (float)D_MODEL;
  float mu  = s * inv;
  float var = sq * inv - mu * mu;
  float rs  = 1.f / sqrtf(var + 1e-5f);
  float4 g1 = *(const float4*)(gamma + tid * 8);
  float4 g2 = *(const float4*)(gamma + tid * 8 + 4);
  float4 b1v = *(const float4*)(beta + tid * 8);
  float4 b2v = *(const float4*)(beta + tid * 8 + 4);
  a.x = (a.x - mu) * rs * g1.x + b1v.x;
  a.y = (a.y - mu) * rs * g1.y + b1v.y;
  a.z = (a.z - mu) * rs * g1.z + b1v.z;
  a.w = (a.w - mu) * rs * g1.w + b1v.w;
  b.x = (b.x - mu) * rs * g2.x + b2v.x;
  b.y = (b.y - mu) * rs * g2.y + b2v.y;
  b.z = (b.z - mu) * rs * g2.z + b2v.z;
  b.w = (b.w - mu) * rs * g2.w + b2v.w;
  float* row = out + (long)t * D_MODEL;
  *(float4*)(row + tid * 8)     = a;
  *(float4*)(row + tid * 8 + 4) = b;
}

// ---------------- launch ----------------

extern "C" void kernel_launch(void* const* d_in, const int* in_sizes, int n_in,
                              void* d_out, int out_size, void* d_ws, size_t ws_size,
                              hipStream_t stream) {
  const float* x     = (const float*)d_in[0];
  const float* Wr    = (const float*)d_in[1];
  const float* W1    = (const float*)d_in[2];
  const float* W2    = (const float*)d_in[3];
  const float* gamma = (const float*)d_in[4];
  const float* beta  = (const float*)d_in[5];
  float* out = (float*)d_out;

  char* ws = (char*)d_ws;
  unsigned short* xb     = (unsigned short*)(ws + 0);          // 12,582,912
  unsigned short* hbuf   = (unsigned short*)(ws + 12582912);   //  8,388,608
  float*          sbuf   = (float*)(ws + 20971520);            // 50,331,648
  int*   topidx   = (int*)  (ws + 71303168);                   // 32,768
  float* topw     = (float*)(ws + 71335936);                   // 32,768
  int*   counts   = (int*)  (ws + 71368704);                   // 256
  int*   cursor   = (int*)  (ws + 71368960);                   // 256
  int*   offs     = (int*)  (ws + 71369216);                   // 512
  int*   tok2slot = (int*)  (ws + 71369728);                   // 32,768
  int*   perm     = (int*)  (ws + 71402496);                   // 32,768
  float* wgt      = (float*)(ws + 71435264);                   // 32,768

  hipLaunchKernelGGL(zero_small_kernel, dim3(1), dim3(64), 0, stream, counts);
  hipLaunchKernelGGL(router_kernel, dim3(NTOK / 8), dim3(256), 0, stream, x, Wr, topidx, topw, counts, xb);
  hipLaunchKernelGGL(scan_kernel, dim3(1), dim3(64), 0, stream, counts, offs, cursor);
  hipLaunchKernelGGL(scatter_kernel, dim3(NTOK / 256), dim3(256), 0, stream, topidx, topw, offs, cursor, perm, wgt, tok2slot);
  hipLaunchKernelGGL(ffn1_kernel, dim3(NEXP, 16), dim3(256), 0, stream, xb, W1, offs, perm, wgt, hbuf);
  hipLaunchKernelGGL(ffn2_kernel, dim3(NEXP, 24), dim3(256), 0, stream, hbuf, W2, offs, sbuf);
  hipLaunchKernelGGL(ln_kernel, dim3(NTOK), dim3(192), 0, stream, sbuf, tok2slot, out, gamma, beta);
}

// Round 6
// 285.616 us; speedup vs baseline: 1.4013x; 1.4013x over previous
//
#include <hip/hip_runtime.h>
#include <hip/hip_bf16.h>

#define D_MODEL 1536
#define NEXP    64
#define D_HID   512
#define NTOK    4096
#define NK1     (D_MODEL / 64)   // 24
#define NK2     (D_HID / 64)     // 8
#define MT      192              // packed M rows per block pass
#define LDSA    (MT * 64)        // 12288 elems
#define LDSB    (64 * 64)        // 4096 elems
#define BUF     (LDSA + LDSB)    // 16384 elems -> 32KB per buffer, 64KB dbuf

typedef __attribute__((ext_vector_type(8))) short short8;
typedef __attribute__((ext_vector_type(4))) float f32x4;

__device__ __forceinline__ unsigned short f2bf(float f) {
  unsigned u = __builtin_bit_cast(unsigned, f);
  u += 0x7FFFu + ((u >> 16) & 1u);
  return (unsigned short)(u >> 16);
}

__device__ __forceinline__ unsigned pk2(float a, float b) {
  return (unsigned)f2bf(a) | ((unsigned)f2bf(b) << 16);
}

// ---------------- utility ----------------

__global__ void zero_small_kernel(int* __restrict__ counts) {
  counts[threadIdx.x] = 0;
}

// ---------------- router (fp32, LDS-tiled, 8 tokens/block, fused x->bf16) ----------------

__global__ __launch_bounds__(256) void router_kernel(const float* __restrict__ x,
    const float* __restrict__ Wr, int* __restrict__ topidx, float* __restrict__ topw,
    int* __restrict__ counts, unsigned short* __restrict__ xb)
{
  __shared__ float xs[8][32];
  __shared__ float wst[32][64];
  const int tid  = threadIdx.x;
  const int lane = tid & 63;
  const int wv   = tid >> 6;
  const int t0   = blockIdx.x * 8;

  float acc[2][4];
  #pragma unroll
  for (int i = 0; i < 2; ++i)
    #pragma unroll
    for (int j = 0; j < 4; ++j) acc[i][j] = 0.f;

  for (int k0 = 0; k0 < D_MODEL; k0 += 32) {
    __syncthreads();
    {
      int r = tid >> 5, c = tid & 31;
      float xv = x[(long)(t0 + r) * D_MODEL + k0 + c];
      xs[r][c] = xv;
      xb[(long)(t0 + r) * D_MODEL + k0 + c] = f2bf(xv);   // fused conversion
    }
    {
      int e = tid >> 2, q = tid & 3;
      const float* wp = Wr + (long)e * D_MODEL + k0 + q * 8;
      float4 v0 = *(const float4*)wp;
      float4 v1 = *(const float4*)(wp + 4);
      int kk = q * 8;
      wst[kk + 0][e] = v0.x; wst[kk + 1][e] = v0.y; wst[kk + 2][e] = v0.z; wst[kk + 3][e] = v0.w;
      wst[kk + 4][e] = v1.x; wst[kk + 5][e] = v1.y; wst[kk + 6][e] = v1.z; wst[kk + 7][e] = v1.w;
    }
    __syncthreads();
    #pragma unroll
    for (int k = 0; k < 32; k += 4) {
      #pragma unroll
      for (int kb = 0; kb < 4; ++kb) {
        float wvv = wst[k + kb][lane];
        #pragma unroll
        for (int i = 0; i < 2; ++i)
          acc[i][kb] = fmaf(xs[wv * 2 + i][k + kb], wvv, acc[i][kb]);
      }
    }
  }
  float lg[2];
  #pragma unroll
  for (int i = 0; i < 2; ++i) lg[i] = (acc[i][0] + acc[i][1]) + (acc[i][2] + acc[i][3]);

  for (int i = 0; i < 2; ++i) {
    float v = lg[i];
    float v0 = v; int e0 = lane;
    #pragma unroll
    for (int off = 32; off > 0; off >>= 1) {
      float ov = __shfl_xor(v0, off);
      int   oe = __shfl_xor(e0, off);
      if (ov > v0 || (ov == v0 && oe < e0)) { v0 = ov; e0 = oe; }
    }
    float v1 = (lane == e0) ? -3.0e38f : v;
    int e1 = lane;
    #pragma unroll
    for (int off = 32; off > 0; off >>= 1) {
      float ov = __shfl_xor(v1, off);
      int   oe = __shfl_xor(e1, off);
      if (ov > v1 || (ov == v1 && oe < e1)) { v1 = ov; e1 = oe; }
    }
    if (lane == 0) {
      int t = t0 + wv * 2 + i;
      float w0 = 1.f / (1.f + expf(v1 - v0));
      topidx[t * 2]     = e0;
      topidx[t * 2 + 1] = e1;
      topw[t * 2]       = w0;
      topw[t * 2 + 1]   = 1.f - w0;
      atomicAdd(&counts[e0], 1);
      atomicAdd(&counts[e1], 1);
    }
  }
}

// ---------------- scan + scatter ----------------

__global__ void scan_kernel(const int* __restrict__ counts, int* __restrict__ offs,
                            int* __restrict__ cursor)
{
  int e = threadIdx.x;   // 64 threads
  int c = counts[e];
  int xx = c;
  #pragma unroll
  for (int off = 1; off < 64; off <<= 1) {
    int y = __shfl_up(xx, off);
    if (e >= off) xx += y;
  }
  offs[e + 1] = xx;
  if (e == 0) offs[0] = 0;
  cursor[e] = 0;
}

__global__ void scatter_kernel(const int* __restrict__ topidx, const float* __restrict__ topw,
    const int* __restrict__ offs, int* __restrict__ cursor,
    int* __restrict__ perm, float* __restrict__ wgt, int* __restrict__ tok2slot)
{
  int t = blockIdx.x * blockDim.x + threadIdx.x;
  if (t >= NTOK) return;
  #pragma unroll
  for (int k = 0; k < 2; ++k) {
    int e = topidx[t * 2 + k];
    float w = topw[t * 2 + k];
    int pos = atomicAdd(&cursor[e], 1);
    int slot = offs[e] + pos;
    perm[slot] = t;
    wgt[slot] = w;
    tok2slot[t * 2 + k] = slot;
  }
}

// ---------------- grouped FFN GEMMs (A+B in LDS, 2-deep register prefetch) ----------------

__global__ __launch_bounds__(256, 2) void ffn1_kernel(
    const unsigned short* __restrict__ xb, const float* __restrict__ W1,
    const int* __restrict__ offs, const int* __restrict__ perm,
    const float* __restrict__ wgt, unsigned short* __restrict__ hbuf)
{
  const int e  = blockIdx.x;
  const int nc = blockIdx.y;                  // 0..7 : 64-col chunk of D_HID
  const int cnt = offs[e + 1] - offs[e];
  if (cnt == 0) return;

  __shared__ unsigned short lds[2 * BUF];

  const int tid = threadIdx.x;
  const int lane = tid & 63;
  const int wv = tid >> 6;

  // staging roles
  const int sA = tid & 7;
  const int rA = tid >> 3;
  const int qB = tid & 15;
  const int rB = tid >> 4;
  const float* bptr[4];
  #pragma unroll
  for (int p = 0; p < 4; ++p)
    bptr[p] = W1 + ((long)e * D_HID + nc * 64 + p * 16 + rB) * D_MODEL + qB * 4;

  // fragment addresses
  int arow[3], brow[4];
  int physA[2][3], physB[2][4];
  #pragma unroll
  for (int mi = 0; mi < 3; ++mi) {
    arow[mi] = wv * 48 + mi * 16 + (lane & 15);
    #pragma unroll
    for (int ks = 0; ks < 2; ++ks)
      physA[ks][mi] = (ks * 4 + (lane >> 4)) ^ (arow[mi] & 7);
  }
  #pragma unroll
  for (int ni = 0; ni < 4; ++ni) {
    brow[ni] = ni * 16 + (lane & 15);
    #pragma unroll
    for (int ks = 0; ks < 2; ++ks)
      physB[ks][ni] = (ks * 4 + (lane >> 4)) ^ (brow[ni] & 7);
  }

  for (int m0 = 0; m0 < cnt; m0 += MT) {
    const int base = offs[e] + m0;
    const int mcnt = min(MT, cnt - m0);

    const unsigned short* aptr[6];
    #pragma unroll
    for (int p = 0; p < 6; ++p) {
      int pr = p * 32 + rA;
      aptr[p] = (pr < mcnt) ? xb + (long)perm[base + pr] * D_MODEL + sA * 8 : nullptr;
    }

    f32x4 acc[3][4];
    #pragma unroll
    for (int i = 0; i < 3; ++i)
      #pragma unroll
      for (int j = 0; j < 4; ++j) acc[i][j] = (f32x4)0.f;

    uint4 a0[6], a1[6]; float4 b0[4], b1[4];

    auto LOAD = [&](uint4* ar, float4* br, int k0) {
      #pragma unroll
      for (int p = 0; p < 6; ++p)
        ar[p] = aptr[p] ? *(const uint4*)(aptr[p] + k0) : make_uint4(0u, 0u, 0u, 0u);
      #pragma unroll
      for (int p = 0; p < 4; ++p)
        br[p] = *(const float4*)(bptr[p] + k0);
    };
    auto WRITE = [&](const uint4* ar, const float4* br, int b) {
      unsigned short* A_ = lds + b * BUF;
      unsigned short* B_ = A_ + LDSA;
      #pragma unroll
      for (int p = 0; p < 6; ++p) {
        int pr = p * 32 + rA;
        *(uint4*)(A_ + pr * 64 + (sA ^ (pr & 7)) * 8) = ar[p];
      }
      #pragma unroll
      for (int p = 0; p < 4; ++p) {
        int rr = p * 16 + rB;
        unsigned lo = pk2(br[p].x, br[p].y);
        unsigned hi = pk2(br[p].z, br[p].w);
        int ph = (qB >> 1) ^ (rr & 7);
        *(uint2*)(B_ + rr * 64 + ph * 8 + (qB & 1) * 4) = make_uint2(lo, hi);
      }
    };
    auto COMPUTE = [&](int b) {
      const unsigned short* A_ = lds + b * BUF;
      const unsigned short* B_ = A_ + LDSA;
      #pragma unroll
      for (int ks = 0; ks < 2; ++ks) {
        short8 a[3], bb[4];
        #pragma unroll
        for (int mi = 0; mi < 3; ++mi)
          a[mi] = *(const short8*)(A_ + arow[mi] * 64 + physA[ks][mi] * 8);
        #pragma unroll
        for (int ni = 0; ni < 4; ++ni)
          bb[ni] = *(const short8*)(B_ + brow[ni] * 64 + physB[ks][ni] * 8);
        #pragma unroll
        for (int mi = 0; mi < 3; ++mi)
          #pragma unroll
          for (int ni = 0; ni < 4; ++ni)
            acc[mi][ni] = __builtin_amdgcn_mfma_f32_16x16x32_bf16(a[mi], bb[ni], acc[mi][ni], 0, 0, 0);
      }
    };

    // prologue: tiles 0 and 1 in flight, tile 0 staged
    LOAD(a0, b0, 0);
    LOAD(a1, b1, 64);
    WRITE(a0, b0, 0);
    __syncthreads();
    #pragma unroll 1
    for (int t = 0; t < NK1; t += 2) {
      WRITE(a1, b1, 1);                                        // tile t+1
      if (t + 2 < NK1) LOAD(a0, b0, (t + 2) * 64);             // tile t+2
      COMPUTE(0);                                              // tile t
      __syncthreads();
      if (t + 2 < NK1) WRITE(a0, b0, 0);                       // tile t+2
      if (t + 3 < NK1) LOAD(a1, b1, (t + 3) * 64);             // tile t+3
      COMPUTE(1);                                              // tile t+1
      __syncthreads();
    }

    // epilogue: SiLU * gate -> bf16 hbuf
    const int rsub = (lane >> 4) * 4;
    const int csub = lane & 15;
    #pragma unroll
    for (int mi = 0; mi < 3; ++mi) {
      #pragma unroll
      for (int rg = 0; rg < 4; ++rg) {
        int r = wv * 48 + mi * 16 + rsub + rg;
        if (r < mcnt) {
          float wt = wgt[base + r];
          unsigned short* hrow = hbuf + (long)(base + r) * D_HID + nc * 64 + csub;
          #pragma unroll
          for (int ni = 0; ni < 4; ++ni) {
            float v = acc[mi][ni][rg];
            float sv = v / (1.f + __expf(-v)) * wt;
            hrow[ni * 16] = f2bf(sv);
          }
        }
      }
    }
    __syncthreads();
  }
}

__global__ __launch_bounds__(256, 2) void ffn2_kernel(
    const unsigned short* __restrict__ hbuf, const float* __restrict__ W2,
    const int* __restrict__ offs, float* __restrict__ sbuf)
{
  const int e  = blockIdx.x;
  const int nc = blockIdx.y;                  // 0..23 : 64-col chunk of D_MODEL
  const int cnt = offs[e + 1] - offs[e];
  if (cnt == 0) return;

  __shared__ unsigned short lds[2 * BUF];

  const int tid = threadIdx.x;
  const int lane = tid & 63;
  const int wv = tid >> 6;

  const int sA = tid & 7;
  const int rA = tid >> 3;
  const int qB = tid & 15;
  const int rB = tid >> 4;
  const float* bptr[4];
  #pragma unroll
  for (int p = 0; p < 4; ++p)
    bptr[p] = W2 + ((long)e * D_MODEL + nc * 64 + p * 16 + rB) * D_HID + qB * 4;

  int arow[3], brow[4];
  int physA[2][3], physB[2][4];
  #pragma unroll
  for (int mi = 0; mi < 3; ++mi) {
    arow[mi] = wv * 48 + mi * 16 + (lane & 15);
    #pragma unroll
    for (int ks = 0; ks < 2; ++ks)
      physA[ks][mi] = (ks * 4 + (lane >> 4)) ^ (arow[mi] & 7);
  }
  #pragma unroll
  for (int ni = 0; ni < 4; ++ni) {
    brow[ni] = ni * 16 + (lane & 15);
    #pragma unroll
    for (int ks = 0; ks < 2; ++ks)
      physB[ks][ni] = (ks * 4 + (lane >> 4)) ^ (brow[ni] & 7);
  }

  for (int m0 = 0; m0 < cnt; m0 += MT) {
    const int base = offs[e] + m0;
    const int mcnt = min(MT, cnt - m0);

    const unsigned short* aptr[6];
    #pragma unroll
    for (int p = 0; p < 6; ++p) {
      int pr = p * 32 + rA;
      aptr[p] = (pr < mcnt) ? hbuf + (long)(base + pr) * D_HID + sA * 8 : nullptr;
    }

    f32x4 acc[3][4];
    #pragma unroll
    for (int i = 0; i < 3; ++i)
      #pragma unroll
      for (int j = 0; j < 4; ++j) acc[i][j] = (f32x4)0.f;

    uint4 a0[6], a1[6]; float4 b0[4], b1[4];

    auto LOAD = [&](uint4* ar, float4* br, int k0) {
      #pragma unroll
      for (int p = 0; p < 6; ++p)
        ar[p] = aptr[p] ? *(const uint4*)(aptr[p] + k0) : make_uint4(0u, 0u, 0u, 0u);
      #pragma unroll
      for (int p = 0; p < 4; ++p)
        br[p] = *(const float4*)(bptr[p] + k0);
    };
    auto WRITE = [&](const uint4* ar, const float4* br, int b) {
      unsigned short* A_ = lds + b * BUF;
      unsigned short* B_ = A_ + LDSA;
      #pragma unroll
      for (int p = 0; p < 6; ++p) {
        int pr = p * 32 + rA;
        *(uint4*)(A_ + pr * 64 + (sA ^ (pr & 7)) * 8) = ar[p];
      }
      #pragma unroll
      for (int p = 0; p < 4; ++p) {
        int rr = p * 16 + rB;
        unsigned lo = pk2(br[p].x, br[p].y);
        unsigned hi = pk2(br[p].z, br[p].w);
        int ph = (qB >> 1) ^ (rr & 7);
        *(uint2*)(B_ + rr * 64 + ph * 8 + (qB & 1) * 4) = make_uint2(lo, hi);
      }
    };
    auto COMPUTE = [&](int b) {
      const unsigned short* A_ = lds + b * BUF;
      const unsigned short* B_ = A_ + LDSA;
      #pragma unroll
      for (int ks = 0; ks < 2; ++ks) {
        short8 a[3], bb[4];
        #pragma unroll
        for (int mi = 0; mi < 3; ++mi)
          a[mi] = *(const short8*)(A_ + arow[mi] * 64 + physA[ks][mi] * 8);
        #pragma unroll
        for (int ni = 0; ni < 4; ++ni)
          bb[ni] = *(const short8*)(B_ + brow[ni] * 64 + physB[ks][ni] * 8);
        #pragma unroll
        for (int mi = 0; mi < 3; ++mi)
          #pragma unroll
          for (int ni = 0; ni < 4; ++ni)
            acc[mi][ni] = __builtin_amdgcn_mfma_f32_16x16x32_bf16(a[mi], bb[ni], acc[mi][ni], 0, 0, 0);
      }
    };

    LOAD(a0, b0, 0);
    LOAD(a1, b1, 64);
    WRITE(a0, b0, 0);
    __syncthreads();
    #pragma unroll 1
    for (int t = 0; t < NK2; t += 2) {
      WRITE(a1, b1, 1);
      if (t + 2 < NK2) LOAD(a0, b0, (t + 2) * 64);
      COMPUTE(0);
      __syncthreads();
      if (t + 2 < NK2) WRITE(a0, b0, 0);
      if (t + 3 < NK2) LOAD(a1, b1, (t + 3) * 64);
      COMPUTE(1);
      __syncthreads();
    }

    // epilogue: LDS transpose -> coalesced float4 stores into slot buffer
    __syncthreads();
    float* fds = (float*)lds;
    const int rsub = (lane >> 4) * 4;
    const int csub = lane & 15;
    #pragma unroll
    for (int mi = 0; mi < 3; ++mi) {
      #pragma unroll
      for (int rg = 0; rg < 4; ++rg) {
        int r = wv * 48 + mi * 16 + rsub + rg;
        #pragma unroll
        for (int ni = 0; ni < 4; ++ni)
          fds[r * 64 + ni * 16 + csub] = acc[mi][ni][rg];
      }
    }
    __syncthreads();
    #pragma unroll
    for (int q = 0; q < 12; ++q) {
      int f4 = q * 256 + tid;
      int row = f4 >> 4, c4 = f4 & 15;
      if (row < mcnt)
        *(float4*)(sbuf + (long)(base + row) * D_MODEL + nc * 64 + c4 * 4) =
            *(const float4*)(fds + row * 64 + c4 * 4);
    }
    __syncthreads();   // protect LDS before next pass
  }
}

// ---------------- gather + LayerNorm ----------------

__global__ __launch_bounds__(192) void ln_kernel(const float* __restrict__ sbuf,
    const int* __restrict__ tok2slot, float* __restrict__ out,
    const float* __restrict__ gamma, const float* __restrict__ beta)
{
  const int tid = threadIdx.x;
  const int t = blockIdx.x;
  const long r0 = (long)tok2slot[t * 2]     * D_MODEL;
  const long r1 = (long)tok2slot[t * 2 + 1] * D_MODEL;

  float4 a0 = *(const float4*)(sbuf + r0 + tid * 8);
  float4 a1 = *(const float4*)(sbuf + r0 + tid * 8 + 4);
  float4 b0 = *(const float4*)(sbuf + r1 + tid * 8);
  float4 b1 = *(const float4*)(sbuf + r1 + tid * 8 + 4);
  float4 a = make_float4(a0.x + b0.x, a0.y + b0.y, a0.z + b0.z, a0.w + b0.w);
  float4 b = make_float4(a1.x + b1.x, a1.y + b1.y, a1.z + b1.z, a1.w + b1.w);

  float s  = ((a.x + a.y) + (a.z + a.w)) + ((b.x + b.y) + (b.z + b.w));
  float sq = ((a.x * a.x + a.y * a.y) + (a.z * a.z + a.w * a.w)) +
             ((b.x * b.x + b.y * b.y) + (b.z * b.z + b.w * b.w));
  #pragma unroll
  for (int off = 32; off > 0; off >>= 1) {
    s  += __shfl_xor(s, off);
    sq += __shfl_xor(sq, off);
  }
  __shared__ float ss[3], sqs[3];
  int wv = tid >> 6;
  if ((tid & 63) == 0) { ss[wv] = s; sqs[wv] = sq; }
  __syncthreads();
  s  = ss[0] + ss[1] + ss[2];
  sq = sqs[0] + sqs[1] + sqs[2];
  const float inv = 1.f / (float)D_MODEL;
  float mu  = s * inv;
  float var = sq * inv - mu * mu;
  float rs  = 1.f / sqrtf(var + 1e-5f);
  float4 g1 = *(const float4*)(gamma + tid * 8);
  float4 g2 = *(const float4*)(gamma + tid * 8 + 4);
  float4 b1v = *(const float4*)(beta + tid * 8);
  float4 b2v = *(const float4*)(beta + tid * 8 + 4);
  a.x = (a.x - mu) * rs * g1.x + b1v.x;
  a.y = (a.y - mu) * rs * g1.y + b1v.y;
  a.z = (a.z - mu) * rs * g1.z + b1v.z;
  a.w = (a.w - mu) * rs * g1.w + b1v.w;
  b.x = (b.x - mu) * rs * g2.x + b2v.x;
  b.y = (b.y - mu) * rs * g2.y + b2v.y;
  b.z = (b.z - mu) * rs * g2.z + b2v.z;
  b.w = (b.w - mu) * rs * g2.w + b2v.w;
  float* row = out + (long)t * D_MODEL;
  *(float4*)(row + tid * 8)     = a;
  *(float4*)(row + tid * 8 + 4) = b;
}

// ---------------- launch ----------------

extern "C" void kernel_launch(void* const* d_in, const int* in_sizes, int n_in,
                              void* d_out, int out_size, void* d_ws, size_t ws_size,
                              hipStream_t stream) {
  const float* x     = (const float*)d_in[0];
  const float* Wr    = (const float*)d_in[1];
  const float* W1    = (const float*)d_in[2];
  const float* W2    = (const float*)d_in[3];
  const float* gamma = (const float*)d_in[4];
  const float* beta  = (const float*)d_in[5];
  float* out = (float*)d_out;

  char* ws = (char*)d_ws;
  unsigned short* xb     = (unsigned short*)(ws + 0);          // 12,582,912
  unsigned short* hbuf   = (unsigned short*)(ws + 12582912);   //  8,388,608
  float*          sbuf   = (float*)(ws + 20971520);            // 50,331,648
  int*   topidx   = (int*)  (ws + 71303168);                   // 32,768
  float* topw     = (float*)(ws + 71335936);                   // 32,768
  int*   counts   = (int*)  (ws + 71368704);                   // 256
  int*   cursor   = (int*)  (ws + 71368960);                   // 256
  int*   offs     = (int*)  (ws + 71369216);                   // 512
  int*   tok2slot = (int*)  (ws + 71369728);                   // 32,768
  int*   perm     = (int*)  (ws + 71402496);                   // 32,768
  float* wgt      = (float*)(ws + 71435264);                   // 32,768

  hipLaunchKernelGGL(zero_small_kernel, dim3(1), dim3(64), 0, stream, counts);
  hipLaunchKernelGGL(router_kernel, dim3(NTOK / 8), dim3(256), 0, stream, x, Wr, topidx, topw, counts, xb);
  hipLaunchKernelGGL(scan_kernel, dim3(1), dim3(64), 0, stream, counts, offs, cursor);
  hipLaunchKernelGGL(scatter_kernel, dim3(NTOK / 256), dim3(256), 0, stream, topidx, topw, offs, cursor, perm, wgt, tok2slot);
  hipLaunchKernelGGL(ffn1_kernel, dim3(NEXP, 8), dim3(256), 0, stream, xb, W1, offs, perm, wgt, hbuf);
  hipLaunchKernelGGL(ffn2_kernel, dim3(NEXP, 24), dim3(256), 0, stream, hbuf, W2, offs, sbuf);
  hipLaunchKernelGGL(ln_kernel, dim3(NTOK), dim3(192), 0, stream, sbuf, tok2slot, out, gamma, beta);
}